// Round 9
// baseline (355.716 us; speedup 1.0000x reference)
//
#include <hip/hip_runtime.h>
#include <hip/hip_bf16.h>

#define DI __device__ __forceinline__

#if __has_builtin(__builtin_amdgcn_exp2f)
#define EXP2(x) __builtin_amdgcn_exp2f(x)
#else
#define EXP2(x) exp2f(x)
#endif

namespace {

constexpr int Bc = 2, Tc = 2048, Dc = 2048, Hc = 32, KVHc = 8, HDc = 64;
constexpr int NQKV = Hc * HDc + 2 * KVHc * HDc;  // 3072

typedef __bf16 bf16x8 __attribute__((ext_vector_type(8)));
typedef unsigned short u16x8 __attribute__((ext_vector_type(8)));
typedef unsigned short u16x4 __attribute__((ext_vector_type(4)));
typedef float f32x4 __attribute__((ext_vector_type(4)));

union FragU { u16x8 u; bf16x8 b; u16x4 h[2]; };

DI float bits2f(unsigned int u) {
  union { unsigned int i; float f; } v; v.i = u << 16; return v.f;
}
DI unsigned short f2bits(float f) {
  __hip_bfloat16 h = __float2bfloat16(f);
  return *reinterpret_cast<unsigned short*>(&h);
}

DI void store_out(float* p, float v) { *p = v; }
DI void store_out(__hip_bfloat16* p, float v) { *p = __float2bfloat16(v); }

typedef __attribute__((address_space(1))) void gv_t;
typedef __attribute__((address_space(3))) void lv_t;

// Stage TOTB bytes (tile rows of ROWB bytes, global row stride row_stride_b) into
// LDS via global_load_lds width=16. LDS dest is wave-uniform base + lane*16 (HW),
// so the optional XOR swizzle permutes the GLOBAL source chunk per lane instead:
// LDS slot (row, chunk k) holds global chunk k ^ (row&7)  [ROWB=128 only].
// 256-thread version (attn).
template<int ROWB, int TOTB, bool SWZ = false>
DI void stage_tile(const char* g, long long row_stride_b, char* lds) {
  const int tid = threadIdx.x;
  const int wid = tid >> 6, lane = tid & 63;
#pragma unroll
  for (int it = 0; it < TOTB / 4096; ++it) {
    int off = it * 4096 + wid * 1024 + lane * 16;
    int row = off / ROWB;
    int colb = off % ROWB;
    if (SWZ) colb ^= (row & 7) << 4;  // 16B-chunk XOR swizzle (ROWB=128)
    const char* gp = g + (long long)row * row_stride_b + colb;
    char* lp = lds + it * 4096 + wid * 1024;  // wave-uniform
    __builtin_amdgcn_global_load_lds((gv_t*)gp, (lv_t*)lp, 16, 0, 0);
  }
}

// 512-thread staging, ROWB=128, always chunk-XOR swizzled. TOTB/8192 loads/thread.
template<int TOTB>
DI void stage512(const char* g, long long row_stride_b, char* lds) {
  const int tid = threadIdx.x;
  const int wid = tid >> 6, lane = tid & 63;
#pragma unroll
  for (int it = 0; it < TOTB / 8192; ++it) {
    const int off = it * 8192 + wid * 1024 + lane * 16;
    const int row = off >> 7;
    const int colb = (off & 127) ^ ((row & 7) << 4);
    const char* gp = g + (long long)row * row_stride_b + colb;
    char* lp = lds + it * 8192 + wid * 1024;  // wave-uniform
    __builtin_amdgcn_global_load_lds((gv_t*)gp, (lv_t*)lp, 16, 0, 0);
  }
}

// ---------------- f32 -> bf16 elementwise convert (8 elems/thread) ----------------
__global__ __launch_bounds__(256) void cvt_f32_bf16(
    const float* __restrict__ in, __hip_bfloat16* __restrict__ out) {
  const long long i = ((long long)blockIdx.x * 256 + threadIdx.x) * 8;
  const float4 a = *(const float4*)(in + i);
  const float4 b = *(const float4*)(in + i + 4);
  u16x8 r;
  r[0] = f2bits(a.x); r[1] = f2bits(a.y); r[2] = f2bits(a.z); r[3] = f2bits(a.w);
  r[4] = f2bits(b.x); r[5] = f2bits(b.y); r[6] = f2bits(b.z); r[7] = f2bits(b.w);
  *(u16x8*)((unsigned short*)out + i) = r;
}

// ------------- 64x64 tiled transpose + f32->bf16 convert: out[c][r] = in[r][c] -------------
__global__ __launch_bounds__(256) void transpose_cvt_kernel(
    const float* __restrict__ in, __hip_bfloat16* __restrict__ out, int R, int C) {
  __shared__ unsigned short tile[64][65];
  const int c0 = blockIdx.x * 64, r0 = blockIdx.y * 64;
  const int tid = threadIdx.x;
  const int rr = tid >> 2, seg = (tid & 3) * 16;
  const float* src = in + (long long)(r0 + rr) * C + c0 + seg;
#pragma unroll
  for (int i = 0; i < 16; ++i) tile[rr][seg + i] = f2bits(src[i]);
  __syncthreads();
  unsigned short* dst = (unsigned short*)out + (long long)(c0 + rr) * R + r0 + seg;
#pragma unroll
  for (int i = 0; i < 16; ++i) dst[i] = tile[seg + i][rr];
}

// ---------------- 64x64 tiled bf16 transpose: out[c][r] = in[r][c] ----------------
__global__ __launch_bounds__(256) void transpose_kernel(
    const __hip_bfloat16* __restrict__ in, __hip_bfloat16* __restrict__ out,
    int R, int C) {
  __shared__ unsigned short tile[64][65];
  const long long slice = (long long)R * C;
  const unsigned short* ip = (const unsigned short*)in + (long long)blockIdx.z * slice;
  unsigned short* op = (unsigned short*)out + (long long)blockIdx.z * slice;
  const int c0 = blockIdx.x * 64, r0 = blockIdx.y * 64;
  const int tid = threadIdx.x;
  const int rr = tid >> 2, seg = (tid & 3) * 16;
  const unsigned short* src = ip + (long long)(r0 + rr) * C + c0 + seg;
#pragma unroll
  for (int i = 0; i < 16; ++i) tile[rr][seg + i] = src[i];
  __syncthreads();
  unsigned short* dst = op + (long long)(c0 + rr) * R + r0 + seg;
#pragma unroll
  for (int i = 0; i < 16; ++i) dst[i] = tile[seg + i][rr];
}

// ---------------- GEMM: C[m][n] = sum_k A[m][k]*Bt[n][k] (+bias[n]) ----------------
// Round-13: 256x256 tile, 8 waves (512 thr, 2M x 4N -> wave tile 128x64), BK=64,
// double-buffered LDS (128 KB, 1 block/CU) on the ATTN-PROVEN sync skeleton:
//   top-of-loop stage(kt+1) -> compute(kt) -> vmcnt(0) + barrier.
// Rationale: 64 MFMA/wave per K-tile (~620 cy/SIMD at 2 waves) now COVERS the
// staging latency before the end-drain -- the property the 16-32-MFMA variants
// lacked. Traffic also halves vs 256x128. Frag reads use the proven 128B-row
// chunk-XOR swizzle (conflict-free). Compute split in 4 sub-phases (kk x m-group)
// to bound live VGPRs (~190). WAR proof: stage(kt+1) targets dbuf last read at
// kt-1, sealed by kt-1's vmcnt(0)+__syncthreads (full waitcnt incl lgkm).
// XCD-aware block swizzle kept (G1 192 blocks, G2 128 -- both % 8 == 0).
template <typename OT>
__global__ __launch_bounds__(512, 1) void gemm256(
    const __hip_bfloat16* __restrict__ A, const __hip_bfloat16* __restrict__ Bt,
    const float* __restrict__ bias, OT* __restrict__ C, int M, int N, int K) {
  __shared__ __align__(16) char As[2][32768];  // 256 rows x 64 K bf16 (swizzled)
  __shared__ __align__(16) char Bs[2][32768];  // 256 rows x 64 K bf16 (swizzled)
  const int nwgx = N >> 8;
  const int nwg = nwgx * (M >> 8);
  const int bid0 = blockIdx.y * nwgx + blockIdx.x;
  const int cpx = nwg >> 3;
  const int bid = (bid0 & 7) * cpx + (bid0 >> 3);
  const int n0 = (bid % nwgx) * 256;
  const int m0 = (bid / nwgx) * 256;
  const int tid = threadIdx.x;
  const int wid = tid >> 6, lane = tid & 63;
  const int wr = wid >> 2, wc = wid & 3;  // wave tile: 128 M x 64 N
  const int l15 = lane & 15, quad = lane >> 4;
  const int sw = l15 & 7;

  const char* Ag = (const char*)(A + (long long)m0 * K);
  const char* Bg = (const char*)(Bt + (long long)n0 * K);
  const long long strb = (long long)K * 2;
  const int nkt = K >> 6;

  f32x4 acc[8][4] = {};

  // Prologue: stage K-tile 0 into buffer 0 (8 loads/thread).
  stage512<32768>(Ag, strb, As[0]);
  stage512<32768>(Bg, strb, Bs[0]);
  asm volatile("s_waitcnt vmcnt(0)" ::: "memory");
  __syncthreads();

  for (int kt = 0; kt < nkt; ++kt) {
    const int db = kt & 1;
    // Prefetch next K-tile into the other buffer (released by last iter's barrier).
    if (kt + 1 < nkt) {
      stage512<32768>(Ag + (long long)(kt + 1) * 128, strb, As[db ^ 1]);
      stage512<32768>(Bg + (long long)(kt + 1) * 128, strb, Bs[db ^ 1]);
    }

    const char* ab = As[db] + wr * (128 * 128);   // wave's 128-row A slice
    const char* bb = Bs[db] + wc * (64 * 128);    // wave's 64-row B slice
#pragma unroll
    for (int kk = 0; kk < 2; ++kk) {
      FragU b4[4];
#pragma unroll
      for (int nt = 0; nt < 4; ++nt)
        b4[nt].u = *(const u16x8*)(bb + (nt * 16 + l15) * 128 +
                                   ((((kk << 2) | quad) ^ sw) << 4));
#pragma unroll
      for (int mg = 0; mg < 2; ++mg) {
        FragU a4[4];
#pragma unroll
        for (int mt = 0; mt < 4; ++mt)
          a4[mt].u = *(const u16x8*)(ab + ((mg * 4 + mt) * 16 + l15) * 128 +
                                     ((((kk << 2) | quad) ^ sw) << 4));
        __builtin_amdgcn_s_setprio(1);
#pragma unroll
        for (int mt = 0; mt < 4; ++mt)
#pragma unroll
          for (int nt = 0; nt < 4; ++nt)
            acc[mg * 4 + mt][nt] = __builtin_amdgcn_mfma_f32_16x16x32_bf16(
                a4[mt].b, b4[nt].b, acc[mg * 4 + mt][nt], 0, 0, 0);
        __builtin_amdgcn_s_setprio(0);
      }
    }

    asm volatile("s_waitcnt vmcnt(0)" ::: "memory");  // my prefetch landed in LDS
    __syncthreads();                                  // everyone's landed; buf[db] released
  }

#pragma unroll
  for (int nt = 0; nt < 4; ++nt) {
    const int col = n0 + wc * 64 + nt * 16 + l15;
    const float bv = bias ? bias[col] : 0.f;
#pragma unroll
    for (int mt = 0; mt < 8; ++mt) {
#pragma unroll
      for (int r = 0; r < 4; ++r) {
        const int row = m0 + wr * 128 + mt * 16 + quad * 4 + r;
        store_out(C + (long long)row * N + col, acc[mt][nt][r] + bv);
      }
    }
  }
}

// ---------------- RoPE + reshape (vectorized: one 16B chunk per thread) ----------------
// qkv (B*T, 3072) bf16 -> Q (B,H,T,64) roped*SCL, K (B,KVH,T,64) roped, V raw.
// SCL = (1/sqrt(64)) * log2(e) folded into Q so attention uses exp2.
__global__ __launch_bounds__(384) void rope_reshape(
    const __hip_bfloat16* __restrict__ qkv, const float* __restrict__ cosb,
    const float* __restrict__ sinb, __hip_bfloat16* __restrict__ Qo,
    __hip_bfloat16* __restrict__ Ko, __hip_bfloat16* __restrict__ Vo) {
  constexpr float SCL = 0.125f * 1.44269504088896f;
  const int row = blockIdx.x;            // b*T + t
  const int b = row / Tc, t = row % Tc;
  const unsigned short* src = (const unsigned short*)qkv + (long long)row * NQKV;
  const float* cb = cosb + t * 32;
  const float* sb = sinb + t * 32;
  const int e = (int)threadIdx.x * 8;
  const u16x8 v = *(const u16x8*)(src + e);
  if (e < Hc * HDc) {                         // Q section (scaled)
    const int hh = e >> 6, d = e & 63, ii = d >> 1;
    u16x8 r;
#pragma unroll
    for (int p = 0; p < 4; ++p) {
      const float c = cb[ii + p], s = sb[ii + p];
      const float xe = bits2f(v[2 * p]), xo = bits2f(v[2 * p + 1]);
      r[2 * p] = f2bits((xe * c - xo * s) * SCL);
      r[2 * p + 1] = f2bits((xe * s + xo * c) * SCL);
    }
    const long long idx = (((long long)b * Hc + hh) * Tc + t) * HDc + d;
    *(u16x8*)((unsigned short*)Qo + idx) = r;
  } else if (e < Hc * HDc + KVHc * HDc) {     // K section
    const int e2 = e - Hc * HDc;
    const int kh = e2 >> 6, d = e2 & 63, ii = d >> 1;
    u16x8 r;
#pragma unroll
    for (int p = 0; p < 4; ++p) {
      const float c = cb[ii + p], s = sb[ii + p];
      const float xe = bits2f(v[2 * p]), xo = bits2f(v[2 * p + 1]);
      r[2 * p] = f2bits(xe * c - xo * s);
      r[2 * p + 1] = f2bits(xe * s + xo * c);
    }
    const long long idx = (((long long)b * KVHc + kh) * Tc + t) * HDc + d;
    *(u16x8*)((unsigned short*)Ko + idx) = r;
  } else {                                    // V section (no rope)
    const int e2 = e - (Hc * HDc + KVHc * HDc);
    const int kh = e2 >> 6, d = e2 & 63;
    const long long idx = (((long long)b * KVHc + kh) * Tc + t) * HDc + d;
    *(u16x8*)((unsigned short*)Vo + idx) = v;
  }
}

// ---------------- attention helpers (round-9-proven) ----------------
// Layouts: S^T strip: S[nt][r] has kv = nt*16+quad*4+r, q = wid*16+l15.
// Zero-shuffle PV: kv <-> mfma-k remapped identically on both operands as
// k = quad*8+j <-> kv = (2ks+(j>>2))*16 + quad*4 + (j&3).

DI void mask_diag(f32x4 (&S)[4], int wid, int l15, int quad) {
#pragma unroll
  for (int nt = 0; nt < 4; ++nt)
#pragma unroll
    for (int r = 0; r < 4; ++r)
      if ((nt * 16 + quad * 4 + r) > (wid * 16 + l15)) S[nt][r] = -1e30f;
}

// Online-softmax update (base 2): consumes S in place (becomes p), returns alpha,
// updates m,l, and packs the PV B-fragments (lane-local, zero data movement).
DI float softmax_pack(f32x4 (&S)[4], float& m_i, float& l_i, FragU (&pa)[2]) {
  float mx = fmaxf(fmaxf(S[0][0], S[0][1]), fmaxf(S[0][2], S[0][3]));
#pragma unroll
  for (int nt = 1; nt < 4; ++nt)
    mx = fmaxf(mx, fmaxf(fmaxf(S[nt][0], S[nt][1]), fmaxf(S[nt][2], S[nt][3])));
  mx = fmaxf(mx, __shfl_xor(mx, 16, 64));
  mx = fmaxf(mx, __shfl_xor(mx, 32, 64));
  const float mnew = fmaxf(m_i, mx);
  const float alpha = EXP2(m_i - mnew);  // first tile: exp2(-inf) = 0
  m_i = mnew;
  float sum = 0.f;
#pragma unroll
  for (int nt = 0; nt < 4; ++nt)
#pragma unroll
    for (int r = 0; r < 4; ++r) {
      const float pp = EXP2(S[nt][r] - mnew);
      S[nt][r] = pp;
      sum += pp;
    }
  sum += __shfl_xor(sum, 16, 64);
  sum += __shfl_xor(sum, 32, 64);
  l_i = l_i * alpha + sum;
#pragma unroll
  for (int ks = 0; ks < 2; ++ks)
#pragma unroll
    for (int r = 0; r < 4; ++r) {
      pa[ks].u[r] = f2bits(S[2 * ks][r]);
      pa[ks].u[4 + r] = f2bits(S[2 * ks + 1][r]);
    }
  return alpha;
}

// Single-state kv-tile (used when only q-state B is in causal range).
DI void attn_tile(const char* __restrict__ Ksb, const char* __restrict__ Vsb,
                  const FragU (&qa)[2], f32x4 (&O)[4], float& m_i, float& l_i,
                  bool diag, int wid, int l15, int quad, int sw) {
  f32x4 S[4] = {};
  __builtin_amdgcn_s_setprio(1);
#pragma unroll
  for (int nt = 0; nt < 4; ++nt) {
#pragma unroll
    for (int ks = 0; ks < 2; ++ks) {
      FragU kb;
      kb.u = *(const u16x8*)(Ksb + (nt * 16 + l15) * 128 + ((((ks << 2) | quad) ^ sw) << 4));
      S[nt] = __builtin_amdgcn_mfma_f32_16x16x32_bf16(kb.b, qa[ks].b, S[nt], 0, 0, 0);
    }
  }
  __builtin_amdgcn_s_setprio(0);
  if (diag) mask_diag(S, wid, l15, quad);
  FragU pa[2];
  const float alpha = softmax_pack(S, m_i, l_i, pa);
#pragma unroll
  for (int nt = 0; nt < 4; ++nt)
#pragma unroll
    for (int r = 0; r < 4; ++r) O[nt][r] *= alpha;
  __builtin_amdgcn_s_setprio(1);
#pragma unroll
  for (int nt = 0; nt < 4; ++nt) {
    const char* vrow = Vsb + (nt * 16 + l15) * 128 + ((quad & 1) << 3);
    const int gq = quad >> 1;
#pragma unroll
    for (int ks = 0; ks < 2; ++ks) {
      FragU vb;
      vb.h[0] = *(const u16x4*)(vrow + (((ks * 4 + gq) ^ sw) << 4));
      vb.h[1] = *(const u16x4*)(vrow + (((ks * 4 + gq + 2) ^ sw) << 4));
      O[nt] = __builtin_amdgcn_mfma_f32_16x16x32_bf16(vb.b, pa[ks].b, O[nt], 0, 0, 0);
    }
  }
  __builtin_amdgcn_s_setprio(0);
}

// DUAL-state kv-tile (round-9): both q-states share every K/V fragment read
// (halves LDS traffic) and provide two independent dependence chains.
DI void attn_tile_dual(const char* __restrict__ Ksb, const char* __restrict__ Vsb,
                       const FragU (&qaB)[2], const FragU (&qaA)[2],
                       f32x4 (&OB)[4], f32x4 (&OA)[4],
                       float& mB, float& lB, float& mA, float& lA,
                       bool diagA, int wid, int l15, int quad, int sw) {
  f32x4 SB[4] = {}, SA[4] = {};
  __builtin_amdgcn_s_setprio(1);
#pragma unroll
  for (int nt = 0; nt < 4; ++nt) {
#pragma unroll
    for (int ks = 0; ks < 2; ++ks) {
      FragU kb;
      kb.u = *(const u16x8*)(Ksb + (nt * 16 + l15) * 128 + ((((ks << 2) | quad) ^ sw) << 4));
      SB[nt] = __builtin_amdgcn_mfma_f32_16x16x32_bf16(kb.b, qaB[ks].b, SB[nt], 0, 0, 0);
      SA[nt] = __builtin_amdgcn_mfma_f32_16x16x32_bf16(kb.b, qaA[ks].b, SA[nt], 0, 0, 0);
    }
  }
  __builtin_amdgcn_s_setprio(0);
  if (diagA) mask_diag(SA, wid, l15, quad);
  FragU paB[2], paA[2];
  const float aB = softmax_pack(SB, mB, lB, paB);
  const float aA = softmax_pack(SA, mA, lA, paA);
#pragma unroll
  for (int nt = 0; nt < 4; ++nt)
#pragma unroll
    for (int r = 0; r < 4; ++r) {
      OB[nt][r] *= aB;
      OA[nt][r] *= aA;
    }
  __builtin_amdgcn_s_setprio(1);
#pragma unroll
  for (int nt = 0; nt < 4; ++nt) {
    const char* vrow = Vsb + (nt * 16 + l15) * 128 + ((quad & 1) << 3);
    const int gq = quad >> 1;
#pragma unroll
    for (int ks = 0; ks < 2; ++ks) {
      FragU vb;
      vb.h[0] = *(const u16x4*)(vrow + (((ks * 4 + gq) ^ sw) << 4));
      vb.h[1] = *(const u16x4*)(vrow + (((ks * 4 + gq + 2) ^ sw) << 4));
      OB[nt] = __builtin_amdgcn_mfma_f32_16x16x32_bf16(vb.b, paB[ks].b, OB[nt], 0, 0, 0);
      OA[nt] = __builtin_amdgcn_mfma_f32_16x16x32_bf16(vb.b, paA[ks].b, OA[nt], 0, 0, 0);
    }
  }
  __builtin_amdgcn_s_setprio(0);
}

// ------------- Causal flash attention, paired q-tiles + dual-state interleave -------------
// (round-11 exact: 96.9 us, proven)
__global__ __launch_bounds__(256, 4) void attn_kernel(
    const __hip_bfloat16* __restrict__ Q, const __hip_bfloat16* __restrict__ K,
    const __hip_bfloat16* __restrict__ Vt, __hip_bfloat16* __restrict__ Out) {
  __shared__ __align__(16) char Ks[2][8192];  // 64 kv x 64 hd (swizzled), double-buffered
  __shared__ __align__(16) char Vs[2][8192];  // 64 hd x 64 kv (swizzled), double-buffered

  const int p = blockIdx.x;                       // pair id 0..15
  const int qtA = p, qtB = (Tc / 64 - 1) - p;     // 31 - p
  const int h = blockIdx.y, b = blockIdx.z;
  const int kvh = h >> 2;  // G = 4
  const int tid = threadIdx.x, wid = tid >> 6, lane = tid & 63;
  const int l15 = lane & 15, quad = lane >> 4;
  const int sw = l15 & 7;

  const char* QgA = (const char*)(Q + (((long long)b * Hc + h) * Tc + qtA * 64) * HDc);
  const char* QgB = (const char*)(Q + (((long long)b * Hc + h) * Tc + qtB * 64) * HDc);
  const char* Kg = (const char*)(K + (((long long)b * KVHc + kvh) * Tc) * HDc);
  const char* Vg = (const char*)(Vt + (((long long)b * KVHc + kvh) * HDc) * Tc);

  // Q fragments straight from global: lane reads row (wid*16+l15), 16B chunk (ks*4+quad).
  FragU qaA[2], qaB[2];
#pragma unroll
  for (int ks = 0; ks < 2; ++ks) {
    const int qoff = (wid * 16 + l15) * 128 + (((ks << 2) | quad) << 4);
    qaA[ks].u = *(const u16x8*)(QgA + qoff);
    qaB[ks].u = *(const u16x8*)(QgB + qoff);
  }

  f32x4 OA[4] = {}, OB[4] = {};
  float mA = -1e30f, lA = 0.f, mB = -1e30f, lB = 0.f;

  // Prologue: stage tile 0 into buffer 0.
  stage_tile<128, 8192, true>(Kg, 128, Ks[0]);
  stage_tile<128, 8192, true>(Vg, (long long)Tc * 2, Vs[0]);
  asm volatile("s_waitcnt vmcnt(0)" ::: "memory");
  __syncthreads();

  for (int j = 0; j <= qtB; ++j) {
    const int cur = j & 1;
    if (j < qtB) {
      stage_tile<128, 8192, true>(Kg + (long long)(j + 1) * 8192, 128, Ks[cur ^ 1]);
      stage_tile<128, 8192, true>(Vg + (long long)(j + 1) * 128, (long long)Tc * 2, Vs[cur ^ 1]);
    }

    if (j <= qtA) {  // wave-uniform: A's kv range is a prefix of B's
      attn_tile_dual(Ks[cur], Vs[cur], qaB, qaA, OB, OA, mB, lB, mA, lA,
                     j == qtA, wid, l15, quad, sw);
    } else {
      attn_tile(Ks[cur], Vs[cur], qaB, OB, mB, lB, j == qtB, wid, l15, quad, sw);
    }

    asm volatile("s_waitcnt vmcnt(0)" ::: "memory");  // my prefetch landed in LDS
    __syncthreads();                                  // everyone's landed; buf[cur] released
  }

  // epilogue x2: O^T / l -> Out[b][t][h*64+hd]; r-contiguous -> 8B stores
  const float invA = 1.0f / lA, invB = 1.0f / lB;
  const int tA = qtA * 64 + wid * 16 + l15;
  const int tB = qtB * 64 + wid * 16 + l15;
  unsigned short* obA =
      (unsigned short*)Out + ((long long)b * Tc + tA) * Dc + h * 64 + quad * 4;
  unsigned short* obB =
      (unsigned short*)Out + ((long long)b * Tc + tB) * Dc + h * 64 + quad * 4;
#pragma unroll
  for (int nt = 0; nt < 4; ++nt) {
    u16x4 va, vb;
#pragma unroll
    for (int r = 0; r < 4; ++r) {
      va[r] = f2bits(OA[nt][r] * invA);
      vb[r] = f2bits(OB[nt][r] * invB);
    }
    *(u16x4*)(obA + nt * 16) = va;
    *(u16x4*)(obB + nt * 16) = vb;
  }
}

}  // namespace

extern "C" void kernel_launch(void* const* d_in, const int* in_sizes, int n_in,
                              void* d_out, int out_size, void* d_ws, size_t ws_size,
                              hipStream_t stream) {
  // All inputs/outputs are FLOAT32 per the reference dtypes.
  const float* x_q  = (const float*)d_in[0];
  const float* Wqkv = (const float*)d_in[1];
  const float* Wout = (const float*)d_in[2];
  const float* bout = (const float*)d_in[3];
  const float* rc   = (const float*)d_in[4];
  const float* rs   = (const float*)d_in[5];
  float* out = (float*)d_out;

  // ---- Overlapping bf16 workspace arena (peak 54.6 MB; stream order makes reuse safe) ----
  constexpr size_t SZ_QKV   = (size_t)Bc * Tc * NQKV * 2;        // 25,165,824
  constexpr size_t SZ_XB    = (size_t)Bc * Tc * Dc * 2;          // 16,777,216
  constexpr size_t SZ_QB    = (size_t)Bc * Hc * Tc * HDc * 2;    // 16,777,216
  constexpr size_t SZ_KV    = (size_t)Bc * KVHc * Tc * HDc * 2;  //  4,194,304
  constexpr size_t SZ_AO    = (size_t)Bc * Tc * Dc * 2;          // 16,777,216
  constexpr size_t OFF_QKV   = 0;                    //  0   .. 25.2M
  constexpr size_t OFF_XB    = SZ_QKV;               // 25.2 .. 41.9M
  constexpr size_t OFF_WQKVT = SZ_QKV + SZ_XB;       // 41.9 .. 54.6M
  constexpr size_t OFF_QB    = SZ_QKV;               // reuses xb (dead after G1)
  constexpr size_t OFF_KB    = OFF_QB + SZ_QB;       // reuses WqkvT head (dead after G1)
  constexpr size_t OFF_VTMP  = OFF_KB + SZ_KV;       // 46.1 .. 50.3M
  constexpr size_t OFF_VT    = 0;                    // reuses qkv (dead after R)
  constexpr size_t OFF_AO    = SZ_KV;                // 4.2 .. 21.0M (old qkv region)
  constexpr size_t OFF_WOUTT = OFF_AO + SZ_AO;       // 21.0 .. 29.4M (old Qb head, dead after A)

  char* w = (char*)d_ws;
  __hip_bfloat16* qkv   = (__hip_bfloat16*)(w + OFF_QKV);
  __hip_bfloat16* xb    = (__hip_bfloat16*)(w + OFF_XB);
  __hip_bfloat16* WqkvT = (__hip_bfloat16*)(w + OFF_WQKVT);
  __hip_bfloat16* Qb    = (__hip_bfloat16*)(w + OFF_QB);
  __hip_bfloat16* Kb    = (__hip_bfloat16*)(w + OFF_KB);
  __hip_bfloat16* Vtmp  = (__hip_bfloat16*)(w + OFF_VTMP);
  __hip_bfloat16* Vt    = (__hip_bfloat16*)(w + OFF_VT);
  __hip_bfloat16* AO    = (__hip_bfloat16*)(w + OFF_AO);
  __hip_bfloat16* WoutT = (__hip_bfloat16*)(w + OFF_WOUTT);

  // C1: x_q f32 -> bf16
  cvt_f32_bf16<<<dim3((Bc * Tc * Dc) / (256 * 8)), 256, 0, stream>>>(x_q, xb);

  // T1: W_qkv (D,3072) f32 -> (3072,D) bf16
  transpose_cvt_kernel<<<dim3(NQKV / 64, Dc / 64), 256, 0, stream>>>(Wqkv, WqkvT, Dc, NQKV);

  // G1: qkv = x @ W_qkv  (bf16 out): 256x256 tile -> 12 x 16 = 192 blocks
  gemm256<__hip_bfloat16><<<dim3(NQKV / 256, (Bc * Tc) / 256), 512, 0, stream>>>(
      xb, WqkvT, nullptr, qkv, Bc * Tc, NQKV, Dc);

  // R: split + rope (+ Q pre-scale) + head-major layouts (384 thr = 3072/8 chunks)
  rope_reshape<<<dim3(Bc * Tc), 384, 0, stream>>>(qkv, rc, rs, Qb, Kb, Vtmp);

  // TV: V (B,KVH,T,64) -> V^T (B,KVH,64,T)
  transpose_kernel<<<dim3(HDc / 64, Tc / 64, Bc * KVHc), 256, 0, stream>>>(Vtmp, Vt, Tc, HDc);

  // A: flash attention (paired q-tiles, dual-state interleave, 2-phase K/V pipeline)
  attn_kernel<<<dim3(Tc / 128, Hc, Bc), 256, 0, stream>>>(Qb, Kb, Vt, AO);

  // T2: W_out f32 -> W_out^T bf16
  transpose_cvt_kernel<<<dim3(Dc / 64, Dc / 64), 256, 0, stream>>>(Wout, WoutT, Dc, Dc);

  // G2: out = AO @ W_out + b_out  (f32 out): 8 x 16 = 128 blocks
  gemm256<float><<<dim3(Dc / 256, (Bc * Tc) / 256), 512, 0, stream>>>(
      AO, WoutT, bout, out, Bc * Tc, Dc, Dc);
}

// Round 10
// 309.493 us; speedup vs baseline: 1.1494x; 1.1494x over previous
//
#include <hip/hip_runtime.h>
#include <hip/hip_bf16.h>

#define DI __device__ __forceinline__

#if __has_builtin(__builtin_amdgcn_exp2f)
#define EXP2(x) __builtin_amdgcn_exp2f(x)
#else
#define EXP2(x) exp2f(x)
#endif

namespace {

constexpr int Bc = 2, Tc = 2048, Dc = 2048, Hc = 32, KVHc = 8, HDc = 64;
constexpr int NQKV = Hc * HDc + 2 * KVHc * HDc;  // 3072

typedef __bf16 bf16x8 __attribute__((ext_vector_type(8)));
typedef unsigned short u16x8 __attribute__((ext_vector_type(8)));
typedef unsigned short u16x4 __attribute__((ext_vector_type(4)));
typedef float f32x4 __attribute__((ext_vector_type(4)));

union FragU { u16x8 u; bf16x8 b; u16x4 h[2]; };

DI float bits2f(unsigned int u) {
  union { unsigned int i; float f; } v; v.i = u << 16; return v.f;
}
DI unsigned short f2bits(float f) {
  __hip_bfloat16 h = __float2bfloat16(f);
  return *reinterpret_cast<unsigned short*>(&h);
}

DI void store_out(float* p, float v) { *p = v; }
DI void store_out(__hip_bfloat16* p, float v) { *p = __float2bfloat16(v); }

typedef __attribute__((address_space(1))) void gv_t;
typedef __attribute__((address_space(3))) void lv_t;

// Stage TOTB bytes (tile rows of ROWB bytes, global row stride row_stride_b) into
// LDS via global_load_lds width=16. LDS dest is wave-uniform base + lane*16 (HW),
// so the optional XOR swizzle permutes the GLOBAL source chunk per lane instead:
// LDS slot (row, chunk k) holds global chunk k ^ (row&7)  [ROWB=128 only].
// 256-thread version (gemm).
template<int ROWB, int TOTB, bool SWZ = false>
DI void stage_tile(const char* g, long long row_stride_b, char* lds) {
  const int tid = threadIdx.x;
  const int wid = tid >> 6, lane = tid & 63;
#pragma unroll
  for (int it = 0; it < TOTB / 4096; ++it) {
    int off = it * 4096 + wid * 1024 + lane * 16;
    int row = off / ROWB;
    int colb = off % ROWB;
    if (SWZ) colb ^= (row & 7) << 4;  // 16B-chunk XOR swizzle (ROWB=128)
    const char* gp = g + (long long)row * row_stride_b + colb;
    char* lp = lds + it * 4096 + wid * 1024;  // wave-uniform
    __builtin_amdgcn_global_load_lds((gv_t*)gp, (lv_t*)lp, 16, 0, 0);
  }
}

// 512-thread staging, ROWB=128, always chunk-XOR swizzled. TOTB/8192 loads/thread.
template<int TOTB>
DI void stage512(const char* g, long long row_stride_b, char* lds) {
  const int tid = threadIdx.x;
  const int wid = tid >> 6, lane = tid & 63;
#pragma unroll
  for (int it = 0; it < TOTB / 8192; ++it) {
    const int off = it * 8192 + wid * 1024 + lane * 16;
    const int row = off >> 7;
    const int colb = (off & 127) ^ ((row & 7) << 4);
    const char* gp = g + (long long)row * row_stride_b + colb;
    char* lp = lds + it * 8192 + wid * 1024;  // wave-uniform
    __builtin_amdgcn_global_load_lds((gv_t*)gp, (lv_t*)lp, 16, 0, 0);
  }
}

// ---------------- f32 -> bf16 elementwise convert (8 elems/thread) ----------------
__global__ __launch_bounds__(256) void cvt_f32_bf16(
    const float* __restrict__ in, __hip_bfloat16* __restrict__ out) {
  const long long i = ((long long)blockIdx.x * 256 + threadIdx.x) * 8;
  const float4 a = *(const float4*)(in + i);
  const float4 b = *(const float4*)(in + i + 4);
  u16x8 r;
  r[0] = f2bits(a.x); r[1] = f2bits(a.y); r[2] = f2bits(a.z); r[3] = f2bits(a.w);
  r[4] = f2bits(b.x); r[5] = f2bits(b.y); r[6] = f2bits(b.z); r[7] = f2bits(b.w);
  *(u16x8*)((unsigned short*)out + i) = r;
}

// ------------- 64x64 tiled transpose + f32->bf16 convert: out[c][r] = in[r][c] -------------
__global__ __launch_bounds__(256) void transpose_cvt_kernel(
    const float* __restrict__ in, __hip_bfloat16* __restrict__ out, int R, int C) {
  __shared__ unsigned short tile[64][65];
  const int c0 = blockIdx.x * 64, r0 = blockIdx.y * 64;
  const int tid = threadIdx.x;
  const int rr = tid >> 2, seg = (tid & 3) * 16;
  const float* src = in + (long long)(r0 + rr) * C + c0 + seg;
#pragma unroll
  for (int i = 0; i < 16; ++i) tile[rr][seg + i] = f2bits(src[i]);
  __syncthreads();
  unsigned short* dst = (unsigned short*)out + (long long)(c0 + rr) * R + r0 + seg;
#pragma unroll
  for (int i = 0; i < 16; ++i) dst[i] = tile[seg + i][rr];
}

// ---------------- 64x64 tiled bf16 transpose: out[c][r] = in[r][c] ----------------
__global__ __launch_bounds__(256) void transpose_kernel(
    const __hip_bfloat16* __restrict__ in, __hip_bfloat16* __restrict__ out,
    int R, int C) {
  __shared__ unsigned short tile[64][65];
  const long long slice = (long long)R * C;
  const unsigned short* ip = (const unsigned short*)in + (long long)blockIdx.z * slice;
  unsigned short* op = (unsigned short*)out + (long long)blockIdx.z * slice;
  const int c0 = blockIdx.x * 64, r0 = blockIdx.y * 64;
  const int tid = threadIdx.x;
  const int rr = tid >> 2, seg = (tid & 3) * 16;
  const unsigned short* src = ip + (long long)(r0 + rr) * C + c0 + seg;
#pragma unroll
  for (int i = 0; i < 16; ++i) tile[rr][seg + i] = src[i];
  __syncthreads();
  unsigned short* dst = op + (long long)(c0 + rr) * R + r0 + seg;
#pragma unroll
  for (int i = 0; i < 16; ++i) dst[i] = tile[seg + i][rr];
}

// ---------------- GEMM: C[m][n] = sum_k A[m][k]*Bt[n][k] (+bias[n]) ----------------
// ROUND-11 EXACT (best measured total): 128x128 tile, BK=32, 4 waves 2x2, counted-
// vmcnt double-buffered pipeline. fills issued 2 iterations ahead; raw s_barrier +
// s_waitcnt vmcnt(4) (waits ONLY for the tile about to be computed; never drains to 0
// in the main loop). lgkm drained implicitly (ds_read feeds MFMA before barrier-2).
// XCD-aware block swizzle (grids % 8 == 0 -> bijective).
template <typename OT>
__global__ __launch_bounds__(256) void gemm_bt(
    const __hip_bfloat16* __restrict__ A, const __hip_bfloat16* __restrict__ Bt,
    const float* __restrict__ bias, OT* __restrict__ C, int M, int N, int K) {
  __shared__ __align__(16) char As[2][8192];  // 128 x 32 bf16, double-buffered
  __shared__ __align__(16) char Bs[2][8192];
  const int nwgx = N >> 7;
  const int nwg = nwgx * (M >> 7);
  const int bid0 = blockIdx.y * nwgx + blockIdx.x;
  const int cpx = nwg >> 3;
  const int bid = (bid0 & 7) * cpx + (bid0 >> 3);
  const int n0 = (bid % nwgx) * 128;
  const int m0 = (bid / nwgx) * 128;
  const int tid = threadIdx.x;
  const int wid = tid >> 6, lane = tid & 63;
  const int wm = (wid >> 1) * 64, wn = (wid & 1) * 64;
  const int l15 = lane & 15, quad = lane >> 4;

  const char* Ag = (const char*)(A + (long long)m0 * K);
  const char* Bg = (const char*)(Bt + (long long)n0 * K);
  const long long strb = (long long)K * 2;

  f32x4 acc[4][4] = {};
  const int nk = K >> 5;

  // Prologue: fill both buffers (8 loads/thread outstanding).
  stage_tile<64, 8192>(Ag, strb, As[0]);
  stage_tile<64, 8192>(Bg, strb, Bs[0]);
  stage_tile<64, 8192>(Ag + 64, strb, As[1]);
  stage_tile<64, 8192>(Bg + 64, strb, Bs[1]);

  for (int kt = 0; kt < nk; ++kt) {
    // Wait for fill(kt) only: 4 newer loads (fill kt+1) may stay in flight.
    if (kt < nk - 1) asm volatile("s_waitcnt vmcnt(4)" ::: "memory");
    else             asm volatile("s_waitcnt vmcnt(0)" ::: "memory");
    __builtin_amdgcn_sched_barrier(0);
    __builtin_amdgcn_s_barrier();  // all waves' fill(kt) landed
    __builtin_amdgcn_sched_barrier(0);

    const char* as = As[kt & 1];
    const char* bs = Bs[kt & 1];
    FragU a[4], b[4];
#pragma unroll
    for (int mt = 0; mt < 4; ++mt)
      a[mt].u = *(const u16x8*)(as + ((wm + mt * 16 + l15) * 32 + quad * 8) * 2);
#pragma unroll
    for (int nt = 0; nt < 4; ++nt)
      b[nt].u = *(const u16x8*)(bs + ((wn + nt * 16 + l15) * 32 + quad * 8) * 2);
#pragma unroll
    for (int mt = 0; mt < 4; ++mt)
#pragma unroll
      for (int nt = 0; nt < 4; ++nt)
        acc[mt][nt] =
            __builtin_amdgcn_mfma_f32_16x16x32_bf16(a[mt].b, b[nt].b, acc[mt][nt], 0, 0, 0);

    __builtin_amdgcn_sched_barrier(0);
    __builtin_amdgcn_s_barrier();  // all waves done reading buf(kt&1)
    __builtin_amdgcn_sched_barrier(0);
    if (kt + 2 < nk) {  // refill the buffer just released
      stage_tile<64, 8192>(Ag + (long long)(kt + 2) * 64, strb, As[kt & 1]);
      stage_tile<64, 8192>(Bg + (long long)(kt + 2) * 64, strb, Bs[kt & 1]);
    }
  }

#pragma unroll
  for (int nt = 0; nt < 4; ++nt) {
    const int col = n0 + wn + nt * 16 + l15;
    const float bv = bias ? bias[col] : 0.f;
#pragma unroll
    for (int mt = 0; mt < 4; ++mt) {
#pragma unroll
      for (int r = 0; r < 4; ++r) {
        const int row = m0 + wm + mt * 16 + quad * 4 + r;
        store_out(C + (long long)row * N + col, acc[mt][nt][r] + bv);
      }
    }
  }
}

// ---------------- RoPE + reshape (vectorized: one 16B chunk per thread) ----------------
// qkv (B*T, 3072) bf16 -> Q (B,H,T,64) roped*SCL, K (B,KVH,T,64) roped, V raw.
// SCL = (1/sqrt(64)) * log2(e) folded into Q so attention uses exp2.
__global__ __launch_bounds__(384) void rope_reshape(
    const __hip_bfloat16* __restrict__ qkv, const float* __restrict__ cosb,
    const float* __restrict__ sinb, __hip_bfloat16* __restrict__ Qo,
    __hip_bfloat16* __restrict__ Ko, __hip_bfloat16* __restrict__ Vo) {
  constexpr float SCL = 0.125f * 1.44269504088896f;
  const int row = blockIdx.x;            // b*T + t
  const int b = row / Tc, t = row % Tc;
  const unsigned short* src = (const unsigned short*)qkv + (long long)row * NQKV;
  const float* cb = cosb + t * 32;
  const float* sb = sinb + t * 32;
  const int e = (int)threadIdx.x * 8;
  const u16x8 v = *(const u16x8*)(src + e);
  if (e < Hc * HDc) {                         // Q section (scaled)
    const int hh = e >> 6, d = e & 63, ii = d >> 1;
    u16x8 r;
#pragma unroll
    for (int p = 0; p < 4; ++p) {
      const float c = cb[ii + p], s = sb[ii + p];
      const float xe = bits2f(v[2 * p]), xo = bits2f(v[2 * p + 1]);
      r[2 * p] = f2bits((xe * c - xo * s) * SCL);
      r[2 * p + 1] = f2bits((xe * s + xo * c) * SCL);
    }
    const long long idx = (((long long)b * Hc + hh) * Tc + t) * HDc + d;
    *(u16x8*)((unsigned short*)Qo + idx) = r;
  } else if (e < Hc * HDc + KVHc * HDc) {     // K section
    const int e2 = e - Hc * HDc;
    const int kh = e2 >> 6, d = e2 & 63, ii = d >> 1;
    u16x8 r;
#pragma unroll
    for (int p = 0; p < 4; ++p) {
      const float c = cb[ii + p], s = sb[ii + p];
      const float xe = bits2f(v[2 * p]), xo = bits2f(v[2 * p + 1]);
      r[2 * p] = f2bits(xe * c - xo * s);
      r[2 * p + 1] = f2bits(xe * s + xo * c);
    }
    const long long idx = (((long long)b * KVHc + kh) * Tc + t) * HDc + d;
    *(u16x8*)((unsigned short*)Ko + idx) = r;
  } else {                                    // V section (no rope)
    const int e2 = e - (Hc * HDc + KVHc * HDc);
    const int kh = e2 >> 6, d = e2 & 63;
    const long long idx = (((long long)b * KVHc + kh) * Tc + t) * HDc + d;
    *(u16x8*)((unsigned short*)Vo + idx) = v;
  }
}

// ---------------- attention helpers (round-9-proven, bodies unchanged) ----------------
// Layouts: S^T strip: S[nt][r] has kv = nt*16+quad*4+r, q = w4*16+l15.
// Zero-shuffle PV: kv <-> mfma-k remapped identically on both operands as
// k = quad*8+j <-> kv = (2ks+(j>>2))*16 + quad*4 + (j&3).

DI void mask_diag(f32x4 (&S)[4], int w4, int l15, int quad) {
#pragma unroll
  for (int nt = 0; nt < 4; ++nt)
#pragma unroll
    for (int r = 0; r < 4; ++r)
      if ((nt * 16 + quad * 4 + r) > (w4 * 16 + l15)) S[nt][r] = -1e30f;
}

// Online-softmax update (base 2): consumes S in place (becomes p), returns alpha,
// updates m,l, and packs the PV B-fragments (lane-local, zero data movement).
DI float softmax_pack(f32x4 (&S)[4], float& m_i, float& l_i, FragU (&pa)[2]) {
  float mx = fmaxf(fmaxf(S[0][0], S[0][1]), fmaxf(S[0][2], S[0][3]));
#pragma unroll
  for (int nt = 1; nt < 4; ++nt)
    mx = fmaxf(mx, fmaxf(fmaxf(S[nt][0], S[nt][1]), fmaxf(S[nt][2], S[nt][3])));
  mx = fmaxf(mx, __shfl_xor(mx, 16, 64));
  mx = fmaxf(mx, __shfl_xor(mx, 32, 64));
  const float mnew = fmaxf(m_i, mx);
  const float alpha = EXP2(m_i - mnew);  // first tile: exp2(-inf) = 0
  m_i = mnew;
  float sum = 0.f;
#pragma unroll
  for (int nt = 0; nt < 4; ++nt)
#pragma unroll
    for (int r = 0; r < 4; ++r) {
      const float pp = EXP2(S[nt][r] - mnew);
      S[nt][r] = pp;
      sum += pp;
    }
  sum += __shfl_xor(sum, 16, 64);
  sum += __shfl_xor(sum, 32, 64);
  l_i = l_i * alpha + sum;
#pragma unroll
  for (int ks = 0; ks < 2; ++ks)
#pragma unroll
    for (int r = 0; r < 4; ++r) {
      pa[ks].u[r] = f2bits(S[2 * ks][r]);
      pa[ks].u[4 + r] = f2bits(S[2 * ks + 1][r]);
    }
  return alpha;
}

// Single-state kv-tile (used when only q-state B is in causal range).
DI void attn_tile(const char* __restrict__ Ksb, const char* __restrict__ Vsb,
                  const FragU (&qa)[2], f32x4 (&O)[4], float& m_i, float& l_i,
                  bool diag, int w4, int l15, int quad, int sw) {
  f32x4 S[4] = {};
  __builtin_amdgcn_s_setprio(1);
#pragma unroll
  for (int nt = 0; nt < 4; ++nt) {
#pragma unroll
    for (int ks = 0; ks < 2; ++ks) {
      FragU kb;
      kb.u = *(const u16x8*)(Ksb + (nt * 16 + l15) * 128 + ((((ks << 2) | quad) ^ sw) << 4));
      S[nt] = __builtin_amdgcn_mfma_f32_16x16x32_bf16(kb.b, qa[ks].b, S[nt], 0, 0, 0);
    }
  }
  __builtin_amdgcn_s_setprio(0);
  if (diag) mask_diag(S, w4, l15, quad);
  FragU pa[2];
  const float alpha = softmax_pack(S, m_i, l_i, pa);
#pragma unroll
  for (int nt = 0; nt < 4; ++nt)
#pragma unroll
    for (int r = 0; r < 4; ++r) O[nt][r] *= alpha;
  __builtin_amdgcn_s_setprio(1);
#pragma unroll
  for (int nt = 0; nt < 4; ++nt) {
    const char* vrow = Vsb + (nt * 16 + l15) * 128 + ((quad & 1) << 3);
    const int gq = quad >> 1;
#pragma unroll
    for (int ks = 0; ks < 2; ++ks) {
      FragU vb;
      vb.h[0] = *(const u16x4*)(vrow + (((ks * 4 + gq) ^ sw) << 4));
      vb.h[1] = *(const u16x4*)(vrow + (((ks * 4 + gq + 2) ^ sw) << 4));
      O[nt] = __builtin_amdgcn_mfma_f32_16x16x32_bf16(vb.b, pa[ks].b, O[nt], 0, 0, 0);
    }
  }
  __builtin_amdgcn_s_setprio(0);
}

// DUAL-state kv-tile (round-9): both q-states share every K/V fragment read
// (halves LDS traffic) and provide two independent dependence chains.
DI void attn_tile_dual(const char* __restrict__ Ksb, const char* __restrict__ Vsb,
                       const FragU (&qaB)[2], const FragU (&qaA)[2],
                       f32x4 (&OB)[4], f32x4 (&OA)[4],
                       float& mB, float& lB, float& mA, float& lA,
                       bool diagA, int w4, int l15, int quad, int sw) {
  f32x4 SB[4] = {}, SA[4] = {};
  __builtin_amdgcn_s_setprio(1);
#pragma unroll
  for (int nt = 0; nt < 4; ++nt) {
#pragma unroll
    for (int ks = 0; ks < 2; ++ks) {
      FragU kb;
      kb.u = *(const u16x8*)(Ksb + (nt * 16 + l15) * 128 + ((((ks << 2) | quad) ^ sw) << 4));
      SB[nt] = __builtin_amdgcn_mfma_f32_16x16x32_bf16(kb.b, qaB[ks].b, SB[nt], 0, 0, 0);
      SA[nt] = __builtin_amdgcn_mfma_f32_16x16x32_bf16(kb.b, qaA[ks].b, SA[nt], 0, 0, 0);
    }
  }
  __builtin_amdgcn_s_setprio(0);
  if (diagA) mask_diag(SA, w4, l15, quad);
  FragU paB[2], paA[2];
  const float aB = softmax_pack(SB, mB, lB, paB);
  const float aA = softmax_pack(SA, mA, lA, paA);
#pragma unroll
  for (int nt = 0; nt < 4; ++nt)
#pragma unroll
    for (int r = 0; r < 4; ++r) {
      OB[nt][r] *= aB;
      OA[nt][r] *= aA;
    }
  __builtin_amdgcn_s_setprio(1);
#pragma unroll
  for (int nt = 0; nt < 4; ++nt) {
    const char* vrow = Vsb + (nt * 16 + l15) * 128 + ((quad & 1) << 3);
    const int gq = quad >> 1;
#pragma unroll
    for (int ks = 0; ks < 2; ++ks) {
      FragU vb;
      vb.h[0] = *(const u16x4*)(vrow + (((ks * 4 + gq) ^ sw) << 4));
      vb.h[1] = *(const u16x4*)(vrow + (((ks * 4 + gq + 2) ^ sw) << 4));
      OB[nt] = __builtin_amdgcn_mfma_f32_16x16x32_bf16(vb.b, paB[ks].b, OB[nt], 0, 0, 0);
      OA[nt] = __builtin_amdgcn_mfma_f32_16x16x32_bf16(vb.b, paA[ks].b, OA[nt], 0, 0, 0);
    }
  }
  __builtin_amdgcn_s_setprio(0);
}

// ------- Causal flash attention, QUAD pairs: 8 waves, 2 pairs/block, shared K/V -------
// Round-14: block p in [0,8) runs 8 waves (512 thr). Wave-group 0 (wid<4) owns pair
// (p, 31-p); group 1 owns (15-p, 16+p). Each group = 33 state-tiles (balanced); kv loop
// = 32-p iterations; K/V staged ONCE per iteration for 4 q-states (staged tiles/head
// drop 392 -> 228, -42%), each barrier covers 2x the MFMA work. Inner bodies and the
// round-8-proven sync skeleton (top-of-loop prefetch -> compute -> vmcnt(0)+barrier)
// are unchanged; only driver indexing differs (per-group qtA/qtB; in-tile row = wid&3).
// Grid 8 x 32 x 2 = 512 blocks = 2/CU x 8 waves = 16 waves/CU (same as round-11).
__global__ __launch_bounds__(512, 4) void attn_kernel(
    const __hip_bfloat16* __restrict__ Q, const __hip_bfloat16* __restrict__ K,
    const __hip_bfloat16* __restrict__ Vt, __hip_bfloat16* __restrict__ Out) {
  __shared__ __align__(16) char Ks[2][8192];  // 64 kv x 64 hd (swizzled), double-buffered
  __shared__ __align__(16) char Vs[2][8192];  // 64 hd x 64 kv (swizzled), double-buffered

  const int p = blockIdx.x;                       // 0..7
  const int h = blockIdx.y, b = blockIdx.z;
  const int kvh = h >> 2;  // G = 4
  const int tid = threadIdx.x, wid = tid >> 6, lane = tid & 63;
  const int w4 = wid & 3, grp = wid >> 2;
  const int l15 = lane & 15, quad = lane >> 4;
  const int sw = l15 & 7;

  const int qtA = grp ? (15 - p) : p;             // group's near tile
  const int qtB = grp ? (16 + p) : (31 - p);      // group's far tile
  const int jmax = 31 - p;                        // block loop bound (= group0's qtB)

  const char* QgA = (const char*)(Q + (((long long)b * Hc + h) * Tc + qtA * 64) * HDc);
  const char* QgB = (const char*)(Q + (((long long)b * Hc + h) * Tc + qtB * 64) * HDc);
  const char* Kg = (const char*)(K + (((long long)b * KVHc + kvh) * Tc) * HDc);
  const char* Vg = (const char*)(Vt + (((long long)b * KVHc + kvh) * HDc) * Tc);

  // Q fragments straight from global: lane reads row (w4*16+l15), 16B chunk (ks*4+quad).
  FragU qaA[2], qaB[2];
#pragma unroll
  for (int ks = 0; ks < 2; ++ks) {
    const int qoff = (w4 * 16 + l15) * 128 + (((ks << 2) | quad) << 4);
    qaA[ks].u = *(const u16x8*)(QgA + qoff);
    qaB[ks].u = *(const u16x8*)(QgB + qoff);
  }

  f32x4 OA[4] = {}, OB[4] = {};
  float mA = -1e30f, lA = 0.f, mB = -1e30f, lB = 0.f;

  // Prologue: stage tile 0 into buffer 0 (512-thread staging: 1 load each).
  stage512<8192>(Kg, 128, Ks[0]);
  stage512<8192>(Vg, (long long)Tc * 2, Vs[0]);
  asm volatile("s_waitcnt vmcnt(0)" ::: "memory");
  __syncthreads();

  for (int j = 0; j <= jmax; ++j) {
    const int cur = j & 1;
    if (j < jmax) {
      stage512<8192>(Kg + (long long)(j + 1) * 8192, 128, Ks[cur ^ 1]);
      stage512<8192>(Vg + (long long)(j + 1) * 128, (long long)Tc * 2, Vs[cur ^ 1]);
    }

    // wave-group-uniform predicates: each group's A range is a prefix of its B range
    if (j <= qtA) {
      attn_tile_dual(Ks[cur], Vs[cur], qaB, qaA, OB, OA, mB, lB, mA, lA,
                     j == qtA, w4, l15, quad, sw);
    } else if (j <= qtB) {
      attn_tile(Ks[cur], Vs[cur], qaB, OB, mB, lB, j == qtB, w4, l15, quad, sw);
    }
    // (group1 idles on j > 16+p tail iterations; still participates in staging+barriers)

    asm volatile("s_waitcnt vmcnt(0)" ::: "memory");  // my prefetch landed in LDS
    __syncthreads();                                  // everyone's landed; buf[cur] released
  }

  // epilogue x2: O^T / l -> Out[b][t][h*64+hd]; r-contiguous -> 8B stores
  const float invA = 1.0f / lA, invB = 1.0f / lB;
  const int tA = qtA * 64 + w4 * 16 + l15;
  const int tB = qtB * 64 + w4 * 16 + l15;
  unsigned short* obA =
      (unsigned short*)Out + ((long long)b * Tc + tA) * Dc + h * 64 + quad * 4;
  unsigned short* obB =
      (unsigned short*)Out + ((long long)b * Tc + tB) * Dc + h * 64 + quad * 4;
#pragma unroll
  for (int nt = 0; nt < 4; ++nt) {
    u16x4 va, vb;
#pragma unroll
    for (int r = 0; r < 4; ++r) {
      va[r] = f2bits(OA[nt][r] * invA);
      vb[r] = f2bits(OB[nt][r] * invB);
    }
    *(u16x4*)(obA + nt * 16) = va;
    *(u16x4*)(obB + nt * 16) = vb;
  }
}

}  // namespace

extern "C" void kernel_launch(void* const* d_in, const int* in_sizes, int n_in,
                              void* d_out, int out_size, void* d_ws, size_t ws_size,
                              hipStream_t stream) {
  // All inputs/outputs are FLOAT32 per the reference dtypes.
  const float* x_q  = (const float*)d_in[0];
  const float* Wqkv = (const float*)d_in[1];
  const float* Wout = (const float*)d_in[2];
  const float* bout = (const float*)d_in[3];
  const float* rc   = (const float*)d_in[4];
  const float* rs   = (const float*)d_in[5];
  float* out = (float*)d_out;

  // ---- Overlapping bf16 workspace arena (peak 54.6 MB; stream order makes reuse safe) ----
  constexpr size_t SZ_QKV   = (size_t)Bc * Tc * NQKV * 2;        // 25,165,824
  constexpr size_t SZ_XB    = (size_t)Bc * Tc * Dc * 2;          // 16,777,216
  constexpr size_t SZ_QB    = (size_t)Bc * Hc * Tc * HDc * 2;    // 16,777,216
  constexpr size_t SZ_KV    = (size_t)Bc * KVHc * Tc * HDc * 2;  //  4,194,304
  constexpr size_t SZ_AO    = (size_t)Bc * Tc * Dc * 2;          // 16,777,216
  constexpr size_t OFF_QKV   = 0;                    //  0   .. 25.2M
  constexpr size_t OFF_XB    = SZ_QKV;               // 25.2 .. 41.9M
  constexpr size_t OFF_WQKVT = SZ_QKV + SZ_XB;       // 41.9 .. 54.6M
  constexpr size_t OFF_QB    = SZ_QKV;               // reuses xb (dead after G1)
  constexpr size_t OFF_KB    = OFF_QB + SZ_QB;       // reuses WqkvT head (dead after G1)
  constexpr size_t OFF_VTMP  = OFF_KB + SZ_KV;       // 46.1 .. 50.3M
  constexpr size_t OFF_VT    = 0;                    // reuses qkv (dead after R)
  constexpr size_t OFF_AO    = SZ_KV;                // 4.2 .. 21.0M (old qkv region)
  constexpr size_t OFF_WOUTT = OFF_AO + SZ_AO;       // 21.0 .. 29.4M (old Qb head, dead after A)

  char* w = (char*)d_ws;
  __hip_bfloat16* qkv   = (__hip_bfloat16*)(w + OFF_QKV);
  __hip_bfloat16* xb    = (__hip_bfloat16*)(w + OFF_XB);
  __hip_bfloat16* WqkvT = (__hip_bfloat16*)(w + OFF_WQKVT);
  __hip_bfloat16* Qb    = (__hip_bfloat16*)(w + OFF_QB);
  __hip_bfloat16* Kb    = (__hip_bfloat16*)(w + OFF_KB);
  __hip_bfloat16* Vtmp  = (__hip_bfloat16*)(w + OFF_VTMP);
  __hip_bfloat16* Vt    = (__hip_bfloat16*)(w + OFF_VT);
  __hip_bfloat16* AO    = (__hip_bfloat16*)(w + OFF_AO);
  __hip_bfloat16* WoutT = (__hip_bfloat16*)(w + OFF_WOUTT);

  // C1: x_q f32 -> bf16
  cvt_f32_bf16<<<dim3((Bc * Tc * Dc) / (256 * 8)), 256, 0, stream>>>(x_q, xb);

  // T1: W_qkv (D,3072) f32 -> (3072,D) bf16
  transpose_cvt_kernel<<<dim3(NQKV / 64, Dc / 64), 256, 0, stream>>>(Wqkv, WqkvT, Dc, NQKV);

  // G1: qkv = x @ W_qkv  (bf16 out)
  gemm_bt<__hip_bfloat16><<<dim3(NQKV / 128, (Bc * Tc) / 128), 256, 0, stream>>>(
      xb, WqkvT, nullptr, qkv, Bc * Tc, NQKV, Dc);

  // R: split + rope (+ Q pre-scale) + head-major layouts (384 thr = 3072/8 chunks)
  rope_reshape<<<dim3(Bc * Tc), 384, 0, stream>>>(qkv, rc, rs, Qb, Kb, Vtmp);

  // TV: V (B,KVH,T,64) -> V^T (B,KVH,64,T)
  transpose_kernel<<<dim3(HDc / 64, Tc / 64, Bc * KVHc), 256, 0, stream>>>(Vtmp, Vt, Tc, HDc);

  // A: flash attention (8 waves, 2 tile-pairs/block, shared K/V staging)
  attn_kernel<<<dim3(Tc / 256, Hc, Bc), 512, 0, stream>>>(Qb, Kb, Vt, AO);

  // T2: W_out f32 -> W_out^T bf16
  transpose_cvt_kernel<<<dim3(Dc / 64, Dc / 64), 256, 0, stream>>>(Wout, WoutT, Dc, Dc);

  // G2: out = AO @ W_out + b_out  (f32 out)
  gemm_bt<float><<<dim3(Dc / 128, (Bc * Tc) / 128), 256, 0, stream>>>(
      AO, WoutT, bout, out, Bc * Tc, Dc, Dc);
}

// Round 11
// 305.946 us; speedup vs baseline: 1.1627x; 1.0116x over previous
//
#include <hip/hip_runtime.h>
#include <hip/hip_bf16.h>

#define DI __device__ __forceinline__

#if __has_builtin(__builtin_amdgcn_exp2f)
#define EXP2(x) __builtin_amdgcn_exp2f(x)
#else
#define EXP2(x) exp2f(x)
#endif

namespace {

constexpr int Bc = 2, Tc = 2048, Dc = 2048, Hc = 32, KVHc = 8, HDc = 64;
constexpr int NQKV = Hc * HDc + 2 * KVHc * HDc;  // 3072
constexpr int VOFF = Hc * HDc + KVHc * HDc;      // 2560 (V section start in qkv row)

typedef __bf16 bf16x8 __attribute__((ext_vector_type(8)));
typedef unsigned short u16x8 __attribute__((ext_vector_type(8)));
typedef unsigned short u16x4 __attribute__((ext_vector_type(4)));
typedef float f32x4 __attribute__((ext_vector_type(4)));

union FragU { u16x8 u; bf16x8 b; u16x4 h[2]; };

DI float bits2f(unsigned int u) {
  union { unsigned int i; float f; } v; v.i = u << 16; return v.f;
}
DI unsigned short f2bits(float f) {
  __hip_bfloat16 h = __float2bfloat16(f);
  return *reinterpret_cast<unsigned short*>(&h);
}

DI void store_out(float* p, float v) { *p = v; }
DI void store_out(__hip_bfloat16* p, float v) { *p = __float2bfloat16(v); }

typedef __attribute__((address_space(1))) void gv_t;
typedef __attribute__((address_space(3))) void lv_t;

// Stage TOTB bytes (tile rows of ROWB bytes, global row stride row_stride_b) into
// LDS via global_load_lds width=16. LDS dest is wave-uniform base + lane*16 (HW).
// 256-thread version (gemm).
template<int ROWB, int TOTB, bool SWZ = false>
DI void stage_tile(const char* g, long long row_stride_b, char* lds) {
  const int tid = threadIdx.x;
  const int wid = tid >> 6, lane = tid & 63;
#pragma unroll
  for (int it = 0; it < TOTB / 4096; ++it) {
    int off = it * 4096 + wid * 1024 + lane * 16;
    int row = off / ROWB;
    int colb = off % ROWB;
    if (SWZ) colb ^= (row & 7) << 4;  // 16B-chunk XOR swizzle (ROWB=128)
    const char* gp = g + (long long)row * row_stride_b + colb;
    char* lp = lds + it * 4096 + wid * 1024;  // wave-uniform
    __builtin_amdgcn_global_load_lds((gv_t*)gp, (lv_t*)lp, 16, 0, 0);
  }
}

// 512-thread staging, ROWB=128, always chunk-XOR swizzled. TOTB/8192 loads/thread.
template<int TOTB>
DI void stage512(const char* g, long long row_stride_b, char* lds) {
  const int tid = threadIdx.x;
  const int wid = tid >> 6, lane = tid & 63;
#pragma unroll
  for (int it = 0; it < TOTB / 8192; ++it) {
    const int off = it * 8192 + wid * 1024 + lane * 16;
    const int row = off >> 7;
    const int colb = (off & 127) ^ ((row & 7) << 4);
    const char* gp = g + (long long)row * row_stride_b + colb;
    char* lp = lds + it * 8192 + wid * 1024;  // wave-uniform
    __builtin_amdgcn_global_load_lds((gv_t*)gp, (lv_t*)lp, 16, 0, 0);
  }
}

// ---------------- PREP: C1 (x f32->bf16) + T1 (W_qkv transpose+cvt), one launch ----------
// Blocks [0,4096): cvt 2048 elems each. Blocks [4096, 4096+1536): 64x64 transpose tiles.
__global__ __launch_bounds__(256) void prep_kernel(
    const float* __restrict__ x_q, __hip_bfloat16* __restrict__ xb,
    const float* __restrict__ Wqkv, __hip_bfloat16* __restrict__ WqkvT) {
  const int tid = threadIdx.x;
  if (blockIdx.x < 4096) {  // C1: x_q -> xb (8 elems/thread)
    const long long i = ((long long)blockIdx.x * 256 + tid) * 8;
    const float4 a = *(const float4*)(x_q + i);
    const float4 b = *(const float4*)(x_q + i + 4);
    u16x8 r;
    r[0] = f2bits(a.x); r[1] = f2bits(a.y); r[2] = f2bits(a.z); r[3] = f2bits(a.w);
    r[4] = f2bits(b.x); r[5] = f2bits(b.y); r[6] = f2bits(b.z); r[7] = f2bits(b.w);
    *(u16x8*)((unsigned short*)xb + i) = r;
  } else {  // T1: Wqkv (Dc,NQKV) f32 -> WqkvT (NQKV,Dc) bf16, 64x64 tile
    __shared__ unsigned short tile[64][65];
    const int bid = blockIdx.x - 4096;
    const int c0 = (bid % (NQKV / 64)) * 64, r0 = (bid / (NQKV / 64)) * 64;
    const int rr = tid >> 2, seg = (tid & 3) * 16;
    const float* src = Wqkv + (long long)(r0 + rr) * NQKV + c0 + seg;
#pragma unroll
    for (int i = 0; i < 16; ++i) tile[rr][seg + i] = f2bits(src[i]);
    __syncthreads();
    unsigned short* dst = (unsigned short*)WqkvT + (long long)(c0 + rr) * Dc + r0 + seg;
#pragma unroll
    for (int i = 0; i < 16; ++i) dst[i] = tile[seg + i][rr];
  }
}

// ------------- 64x64 tiled transpose + f32->bf16 convert: out[c][r] = in[r][c] -------------
// (used for T2: W_out -> W_out^T)
__global__ __launch_bounds__(256) void transpose_cvt_kernel(
    const float* __restrict__ in, __hip_bfloat16* __restrict__ out, int R, int C) {
  __shared__ unsigned short tile[64][65];
  const int c0 = blockIdx.x * 64, r0 = blockIdx.y * 64;
  const int tid = threadIdx.x;
  const int rr = tid >> 2, seg = (tid & 3) * 16;
  const float* src = in + (long long)(r0 + rr) * C + c0 + seg;
#pragma unroll
  for (int i = 0; i < 16; ++i) tile[rr][seg + i] = f2bits(src[i]);
  __syncthreads();
  unsigned short* dst = (unsigned short*)out + (long long)(c0 + rr) * R + r0 + seg;
#pragma unroll
  for (int i = 0; i < 16; ++i) dst[i] = tile[seg + i][rr];
}

// ---------------- GEMM: C[m][n] = sum_k A[m][k]*Bt[n][k] (+bias[n]) ----------------
// ROUND-11 EXACT (best measured): 128x128 tile, BK=32, 4 waves 2x2, counted-vmcnt
// double-buffered pipeline. fills issued 2 iterations ahead; raw s_barrier +
// s_waitcnt vmcnt(4) (never drains to 0 in the main loop). XCD-aware swizzle.
template <typename OT>
__global__ __launch_bounds__(256) void gemm_bt(
    const __hip_bfloat16* __restrict__ A, const __hip_bfloat16* __restrict__ Bt,
    const float* __restrict__ bias, OT* __restrict__ C, int M, int N, int K) {
  __shared__ __align__(16) char As[2][8192];  // 128 x 32 bf16, double-buffered
  __shared__ __align__(16) char Bs[2][8192];
  const int nwgx = N >> 7;
  const int nwg = nwgx * (M >> 7);
  const int bid0 = blockIdx.y * nwgx + blockIdx.x;
  const int cpx = nwg >> 3;
  const int bid = (bid0 & 7) * cpx + (bid0 >> 3);
  const int n0 = (bid % nwgx) * 128;
  const int m0 = (bid / nwgx) * 128;
  const int tid = threadIdx.x;
  const int wid = tid >> 6, lane = tid & 63;
  const int wm = (wid >> 1) * 64, wn = (wid & 1) * 64;
  const int l15 = lane & 15, quad = lane >> 4;

  const char* Ag = (const char*)(A + (long long)m0 * K);
  const char* Bg = (const char*)(Bt + (long long)n0 * K);
  const long long strb = (long long)K * 2;

  f32x4 acc[4][4] = {};
  const int nk = K >> 5;

  // Prologue: fill both buffers (8 loads/thread outstanding).
  stage_tile<64, 8192>(Ag, strb, As[0]);
  stage_tile<64, 8192>(Bg, strb, Bs[0]);
  stage_tile<64, 8192>(Ag + 64, strb, As[1]);
  stage_tile<64, 8192>(Bg + 64, strb, Bs[1]);

  for (int kt = 0; kt < nk; ++kt) {
    // Wait for fill(kt) only: 4 newer loads (fill kt+1) may stay in flight.
    if (kt < nk - 1) asm volatile("s_waitcnt vmcnt(4)" ::: "memory");
    else             asm volatile("s_waitcnt vmcnt(0)" ::: "memory");
    __builtin_amdgcn_sched_barrier(0);
    __builtin_amdgcn_s_barrier();  // all waves' fill(kt) landed
    __builtin_amdgcn_sched_barrier(0);

    const char* as = As[kt & 1];
    const char* bs = Bs[kt & 1];
    FragU a[4], b[4];
#pragma unroll
    for (int mt = 0; mt < 4; ++mt)
      a[mt].u = *(const u16x8*)(as + ((wm + mt * 16 + l15) * 32 + quad * 8) * 2);
#pragma unroll
    for (int nt = 0; nt < 4; ++nt)
      b[nt].u = *(const u16x8*)(bs + ((wn + nt * 16 + l15) * 32 + quad * 8) * 2);
#pragma unroll
    for (int mt = 0; mt < 4; ++mt)
#pragma unroll
      for (int nt = 0; nt < 4; ++nt)
        acc[mt][nt] =
            __builtin_amdgcn_mfma_f32_16x16x32_bf16(a[mt].b, b[nt].b, acc[mt][nt], 0, 0, 0);

    __builtin_amdgcn_sched_barrier(0);
    __builtin_amdgcn_s_barrier();  // all waves done reading buf(kt&1)
    __builtin_amdgcn_sched_barrier(0);
    if (kt + 2 < nk) {  // refill the buffer just released
      stage_tile<64, 8192>(Ag + (long long)(kt + 2) * 64, strb, As[kt & 1]);
      stage_tile<64, 8192>(Bg + (long long)(kt + 2) * 64, strb, Bs[kt & 1]);
    }
  }

#pragma unroll
  for (int nt = 0; nt < 4; ++nt) {
    const int col = n0 + wn + nt * 16 + l15;
    const float bv = bias ? bias[col] : 0.f;
#pragma unroll
    for (int mt = 0; mt < 4; ++mt) {
#pragma unroll
      for (int r = 0; r < 4; ++r) {
        const int row = m0 + wm + mt * 16 + quad * 4 + r;
        store_out(C + (long long)row * N + col, acc[mt][nt][r] + bv);
      }
    }
  }
}

// --------- RT: RoPE (Q,K) + V-transpose-from-qkv, one launch (384 threads) ---------
// Blocks [0, B*T): rope one qkv row -> Q (roped*SCL), K (roped). V skipped here.
// Blocks [B*T, B*T+512): 64x64 t x d transpose tiles: qkv V-section -> Vt (B,KVH,64,T).
__global__ __launch_bounds__(384) void rope_v_kernel(
    const __hip_bfloat16* __restrict__ qkv, const float* __restrict__ cosb,
    const float* __restrict__ sinb, __hip_bfloat16* __restrict__ Qo,
    __hip_bfloat16* __restrict__ Ko, __hip_bfloat16* __restrict__ Vt) {
  constexpr float SCL = 0.125f * 1.44269504088896f;
  const int tid = threadIdx.x;
  if (blockIdx.x < Bc * Tc) {
    const int row = blockIdx.x;            // b*T + t
    const int b = row / Tc, t = row % Tc;
    const unsigned short* src = (const unsigned short*)qkv + (long long)row * NQKV;
    const float* cb = cosb + t * 32;
    const float* sb = sinb + t * 32;
    const int e = tid * 8;
    if (e < Hc * HDc) {                         // Q section (scaled)
      const u16x8 v = *(const u16x8*)(src + e);
      const int hh = e >> 6, d = e & 63, ii = d >> 1;
      u16x8 r;
#pragma unroll
      for (int p = 0; p < 4; ++p) {
        const float c = cb[ii + p], s = sb[ii + p];
        const float xe = bits2f(v[2 * p]), xo = bits2f(v[2 * p + 1]);
        r[2 * p] = f2bits((xe * c - xo * s) * SCL);
        r[2 * p + 1] = f2bits((xe * s + xo * c) * SCL);
      }
      const long long idx = (((long long)b * Hc + hh) * Tc + t) * HDc + d;
      *(u16x8*)((unsigned short*)Qo + idx) = r;
    } else if (e < VOFF) {                      // K section
      const u16x8 v = *(const u16x8*)(src + e);
      const int e2 = e - Hc * HDc;
      const int kh = e2 >> 6, d = e2 & 63, ii = d >> 1;
      u16x8 r;
#pragma unroll
      for (int p = 0; p < 4; ++p) {
        const float c = cb[ii + p], s = sb[ii + p];
        const float xe = bits2f(v[2 * p]), xo = bits2f(v[2 * p + 1]);
        r[2 * p] = f2bits(xe * c - xo * s);
        r[2 * p + 1] = f2bits(xe * s + xo * c);
      }
      const long long idx = (((long long)b * KVHc + kh) * Tc + t) * HDc + d;
      *(u16x8*)((unsigned short*)Ko + idx) = r;
    }
    // V section handled by the transpose blocks below
  } else {
    __shared__ unsigned short tile[64][65];
    const int bid = blockIdx.x - Bc * Tc;       // 0..511
    const int z = bid >> 5;                     // b*KVH + kvh
    const int b = z >> 3, kvh = z & 7;
    const int t0 = (bid & 31) * 64;
    const int rr = (tid & 255) >> 2, seg = (tid & 3) * 16;
    if (tid < 256) {
      const unsigned short* src = (const unsigned short*)qkv +
          (long long)(b * Tc + t0 + rr) * NQKV + VOFF + kvh * 64 + seg;
#pragma unroll
      for (int i = 0; i < 16; ++i) tile[rr][seg + i] = src[i];
    }
    __syncthreads();
    if (tid < 256) {
      unsigned short* dst = (unsigned short*)Vt + ((long long)z * HDc + rr) * Tc + t0 + seg;
#pragma unroll
      for (int i = 0; i < 16; ++i) dst[i] = tile[seg + i][rr];
    }
  }
}

// ---------------- attention helpers (round-9-proven, bodies unchanged) ----------------
// Layouts: S^T strip: S[nt][r] has kv = nt*16+quad*4+r, q = w4*16+l15.
// Zero-shuffle PV: kv <-> mfma-k remapped identically on both operands as
// k = quad*8+j <-> kv = (2ks+(j>>2))*16 + quad*4 + (j&3).

DI void mask_diag(f32x4 (&S)[4], int w4, int l15, int quad) {
#pragma unroll
  for (int nt = 0; nt < 4; ++nt)
#pragma unroll
    for (int r = 0; r < 4; ++r)
      if ((nt * 16 + quad * 4 + r) > (w4 * 16 + l15)) S[nt][r] = -1e30f;
}

// Online-softmax update (base 2): consumes S in place (becomes p), returns alpha,
// updates m,l, and packs the PV B-fragments (lane-local, zero data movement).
DI float softmax_pack(f32x4 (&S)[4], float& m_i, float& l_i, FragU (&pa)[2]) {
  float mx = fmaxf(fmaxf(S[0][0], S[0][1]), fmaxf(S[0][2], S[0][3]));
#pragma unroll
  for (int nt = 1; nt < 4; ++nt)
    mx = fmaxf(mx, fmaxf(fmaxf(S[nt][0], S[nt][1]), fmaxf(S[nt][2], S[nt][3])));
  mx = fmaxf(mx, __shfl_xor(mx, 16, 64));
  mx = fmaxf(mx, __shfl_xor(mx, 32, 64));
  const float mnew = fmaxf(m_i, mx);
  const float alpha = EXP2(m_i - mnew);  // first tile: exp2(-inf) = 0
  m_i = mnew;
  float sum = 0.f;
#pragma unroll
  for (int nt = 0; nt < 4; ++nt)
#pragma unroll
    for (int r = 0; r < 4; ++r) {
      const float pp = EXP2(S[nt][r] - mnew);
      S[nt][r] = pp;
      sum += pp;
    }
  sum += __shfl_xor(sum, 16, 64);
  sum += __shfl_xor(sum, 32, 64);
  l_i = l_i * alpha + sum;
#pragma unroll
  for (int ks = 0; ks < 2; ++ks)
#pragma unroll
    for (int r = 0; r < 4; ++r) {
      pa[ks].u[r] = f2bits(S[2 * ks][r]);
      pa[ks].u[4 + r] = f2bits(S[2 * ks + 1][r]);
    }
  return alpha;
}

// Single-state kv-tile (used when only q-state B is in causal range).
DI void attn_tile(const char* __restrict__ Ksb, const char* __restrict__ Vsb,
                  const FragU (&qa)[2], f32x4 (&O)[4], float& m_i, float& l_i,
                  bool diag, int w4, int l15, int quad, int sw) {
  f32x4 S[4] = {};
  __builtin_amdgcn_s_setprio(1);
#pragma unroll
  for (int nt = 0; nt < 4; ++nt) {
#pragma unroll
    for (int ks = 0; ks < 2; ++ks) {
      FragU kb;
      kb.u = *(const u16x8*)(Ksb + (nt * 16 + l15) * 128 + ((((ks << 2) | quad) ^ sw) << 4));
      S[nt] = __builtin_amdgcn_mfma_f32_16x16x32_bf16(kb.b, qa[ks].b, S[nt], 0, 0, 0);
    }
  }
  __builtin_amdgcn_s_setprio(0);
  if (diag) mask_diag(S, w4, l15, quad);
  FragU pa[2];
  const float alpha = softmax_pack(S, m_i, l_i, pa);
#pragma unroll
  for (int nt = 0; nt < 4; ++nt)
#pragma unroll
    for (int r = 0; r < 4; ++r) O[nt][r] *= alpha;
  __builtin_amdgcn_s_setprio(1);
#pragma unroll
  for (int nt = 0; nt < 4; ++nt) {
    const char* vrow = Vsb + (nt * 16 + l15) * 128 + ((quad & 1) << 3);
    const int gq = quad >> 1;
#pragma unroll
    for (int ks = 0; ks < 2; ++ks) {
      FragU vb;
      vb.h[0] = *(const u16x4*)(vrow + (((ks * 4 + gq) ^ sw) << 4));
      vb.h[1] = *(const u16x4*)(vrow + (((ks * 4 + gq + 2) ^ sw) << 4));
      O[nt] = __builtin_amdgcn_mfma_f32_16x16x32_bf16(vb.b, pa[ks].b, O[nt], 0, 0, 0);
    }
  }
  __builtin_amdgcn_s_setprio(0);
}

// DUAL-state kv-tile (round-9): both q-states share every K/V fragment read
// (halves LDS traffic) and provide two independent dependence chains.
DI void attn_tile_dual(const char* __restrict__ Ksb, const char* __restrict__ Vsb,
                       const FragU (&qaB)[2], const FragU (&qaA)[2],
                       f32x4 (&OB)[4], f32x4 (&OA)[4],
                       float& mB, float& lB, float& mA, float& lA,
                       bool diagA, int w4, int l15, int quad, int sw) {
  f32x4 SB[4] = {}, SA[4] = {};
  __builtin_amdgcn_s_setprio(1);
#pragma unroll
  for (int nt = 0; nt < 4; ++nt) {
#pragma unroll
    for (int ks = 0; ks < 2; ++ks) {
      FragU kb;
      kb.u = *(const u16x8*)(Ksb + (nt * 16 + l15) * 128 + ((((ks << 2) | quad) ^ sw) << 4));
      SB[nt] = __builtin_amdgcn_mfma_f32_16x16x32_bf16(kb.b, qaB[ks].b, SB[nt], 0, 0, 0);
      SA[nt] = __builtin_amdgcn_mfma_f32_16x16x32_bf16(kb.b, qaA[ks].b, SA[nt], 0, 0, 0);
    }
  }
  __builtin_amdgcn_s_setprio(0);
  if (diagA) mask_diag(SA, w4, l15, quad);
  FragU paB[2], paA[2];
  const float aB = softmax_pack(SB, mB, lB, paB);
  const float aA = softmax_pack(SA, mA, lA, paA);
#pragma unroll
  for (int nt = 0; nt < 4; ++nt)
#pragma unroll
    for (int r = 0; r < 4; ++r) {
      OB[nt][r] *= aB;
      OA[nt][r] *= aA;
    }
  __builtin_amdgcn_s_setprio(1);
#pragma unroll
  for (int nt = 0; nt < 4; ++nt) {
    const char* vrow = Vsb + (nt * 16 + l15) * 128 + ((quad & 1) << 3);
    const int gq = quad >> 1;
#pragma unroll
    for (int ks = 0; ks < 2; ++ks) {
      FragU vb;
      vb.h[0] = *(const u16x4*)(vrow + (((ks * 4 + gq) ^ sw) << 4));
      vb.h[1] = *(const u16x4*)(vrow + (((ks * 4 + gq + 2) ^ sw) << 4));
      OB[nt] = __builtin_amdgcn_mfma_f32_16x16x32_bf16(vb.b, paB[ks].b, OB[nt], 0, 0, 0);
      OA[nt] = __builtin_amdgcn_mfma_f32_16x16x32_bf16(vb.b, paA[ks].b, OA[nt], 0, 0, 0);
    }
  }
  __builtin_amdgcn_s_setprio(0);
}

// ------- Causal flash attention, QUAD pairs with MATCHED loop bounds (round-15) -------
// Block p in [0,8), 8 waves. Group0 (wid<4) owns pair (2p, 31-2p); group1 owns
// (2p+1, 30-2p). Both groups = 33 state-tiles and their far tiles differ by 1 ->
// group1 idles at most ONE iteration (round-14's pairing idled up to 15). K/V staged
// once per iteration for 4 q-states. Sync skeleton and inner bodies unchanged.
__global__ __launch_bounds__(512, 4) void attn_kernel(
    const __hip_bfloat16* __restrict__ Q, const __hip_bfloat16* __restrict__ K,
    const __hip_bfloat16* __restrict__ Vt, __hip_bfloat16* __restrict__ Out) {
  __shared__ __align__(16) char Ks[2][8192];  // 64 kv x 64 hd (swizzled), double-buffered
  __shared__ __align__(16) char Vs[2][8192];  // 64 hd x 64 kv (swizzled), double-buffered

  const int p = blockIdx.x;                       // 0..7
  const int h = blockIdx.y, b = blockIdx.z;
  const int kvh = h >> 2;  // G = 4
  const int tid = threadIdx.x, wid = tid >> 6, lane = tid & 63;
  const int w4 = wid & 3, grp = wid >> 2;
  const int l15 = lane & 15, quad = lane >> 4;
  const int sw = l15 & 7;

  const int qtA = 2 * p + grp;                    // group's near tile (0..15 covered)
  const int qtB = 31 - 2 * p - grp;               // group's far tile (16..31 covered)
  const int jmax = 31 - 2 * p;                    // block loop bound (= group0's qtB)

  const char* QgA = (const char*)(Q + (((long long)b * Hc + h) * Tc + qtA * 64) * HDc);
  const char* QgB = (const char*)(Q + (((long long)b * Hc + h) * Tc + qtB * 64) * HDc);
  const char* Kg = (const char*)(K + (((long long)b * KVHc + kvh) * Tc) * HDc);
  const char* Vg = (const char*)(Vt + (((long long)b * KVHc + kvh) * HDc) * Tc);

  // Q fragments straight from global: lane reads row (w4*16+l15), 16B chunk (ks*4+quad).
  FragU qaA[2], qaB[2];
#pragma unroll
  for (int ks = 0; ks < 2; ++ks) {
    const int qoff = (w4 * 16 + l15) * 128 + (((ks << 2) | quad) << 4);
    qaA[ks].u = *(const u16x8*)(QgA + qoff);
    qaB[ks].u = *(const u16x8*)(QgB + qoff);
  }

  f32x4 OA[4] = {}, OB[4] = {};
  float mA = -1e30f, lA = 0.f, mB = -1e30f, lB = 0.f;

  // Prologue: stage tile 0 into buffer 0 (512-thread staging: 1 load each).
  stage512<8192>(Kg, 128, Ks[0]);
  stage512<8192>(Vg, (long long)Tc * 2, Vs[0]);
  asm volatile("s_waitcnt vmcnt(0)" ::: "memory");
  __syncthreads();

  for (int j = 0; j <= jmax; ++j) {
    const int cur = j & 1;
    if (j < jmax) {
      stage512<8192>(Kg + (long long)(j + 1) * 8192, 128, Ks[cur ^ 1]);
      stage512<8192>(Vg + (long long)(j + 1) * 128, (long long)Tc * 2, Vs[cur ^ 1]);
    }

    // wave-group-uniform predicates: each group's A range is a prefix of its B range
    if (j <= qtA) {
      attn_tile_dual(Ks[cur], Vs[cur], qaB, qaA, OB, OA, mB, lB, mA, lA,
                     j == qtA, w4, l15, quad, sw);
    } else if (j <= qtB) {
      attn_tile(Ks[cur], Vs[cur], qaB, OB, mB, lB, j == qtB, w4, l15, quad, sw);
    }
    // (group1 idles only at j == jmax)

    asm volatile("s_waitcnt vmcnt(0)" ::: "memory");  // my prefetch landed in LDS
    __syncthreads();                                  // everyone's landed; buf[cur] released
  }

  // epilogue x2: O^T / l -> Out[b][t][h*64+hd]; r-contiguous -> 8B stores
  const float invA = 1.0f / lA, invB = 1.0f / lB;
  const int tA = qtA * 64 + w4 * 16 + l15;
  const int tB = qtB * 64 + w4 * 16 + l15;
  unsigned short* obA =
      (unsigned short*)Out + ((long long)b * Tc + tA) * Dc + h * 64 + quad * 4;
  unsigned short* obB =
      (unsigned short*)Out + ((long long)b * Tc + tB) * Dc + h * 64 + quad * 4;
#pragma unroll
  for (int nt = 0; nt < 4; ++nt) {
    u16x4 va, vb;
#pragma unroll
    for (int r = 0; r < 4; ++r) {
      va[r] = f2bits(OA[nt][r] * invA);
      vb[r] = f2bits(OB[nt][r] * invB);
    }
    *(u16x4*)(obA + nt * 16) = va;
    *(u16x4*)(obB + nt * 16) = vb;
  }
}

}  // namespace

extern "C" void kernel_launch(void* const* d_in, const int* in_sizes, int n_in,
                              void* d_out, int out_size, void* d_ws, size_t ws_size,
                              hipStream_t stream) {
  // All inputs/outputs are FLOAT32 per the reference dtypes.
  const float* x_q  = (const float*)d_in[0];
  const float* Wqkv = (const float*)d_in[1];
  const float* Wout = (const float*)d_in[2];
  const float* bout = (const float*)d_in[3];
  const float* rc   = (const float*)d_in[4];
  const float* rs   = (const float*)d_in[5];
  float* out = (float*)d_out;

  // ---- Overlapping bf16 workspace arena (peak 54.6 MB) ----
  // Live ranges: x_q->xb [25.2,41.9) until G1; WqkvT [41.9,54.6) until G1;
  // qkv [0,25.2) until RT; Qb [25.2,41.9) (reuses xb) until A; Kb [41.9,46.1) until A;
  // Vt [46.1,50.3) (reuses WqkvT mid) until A; AO [4.2,21.0) (qkv dead) until G2;
  // WoutT [21.0,29.4) (qkv tail + Qb head, both dead when T2 runs after A) until G2.
  constexpr size_t SZ_QKV   = (size_t)Bc * Tc * NQKV * 2;        // 25,165,824
  constexpr size_t SZ_XB    = (size_t)Bc * Tc * Dc * 2;          // 16,777,216
  constexpr size_t SZ_KV    = (size_t)Bc * KVHc * Tc * HDc * 2;  //  4,194,304
  constexpr size_t SZ_AO    = (size_t)Bc * Tc * Dc * 2;          // 16,777,216
  constexpr size_t OFF_QKV   = 0;
  constexpr size_t OFF_XB    = SZ_QKV;
  constexpr size_t OFF_WQKVT = SZ_QKV + SZ_XB;
  constexpr size_t OFF_QB    = SZ_QKV;               // reuses xb (dead after G1)
  constexpr size_t OFF_KB    = OFF_WQKVT;            // reuses WqkvT head (dead after G1)
  constexpr size_t OFF_VT    = OFF_KB + SZ_KV;       // reuses WqkvT mid (dead after G1)
  constexpr size_t OFF_AO    = SZ_KV;                // reuses qkv region (dead after RT)
  constexpr size_t OFF_WOUTT = OFF_AO + SZ_AO;       // qkv tail + Qb head (dead after A)

  char* w = (char*)d_ws;
  __hip_bfloat16* qkv   = (__hip_bfloat16*)(w + OFF_QKV);
  __hip_bfloat16* xb    = (__hip_bfloat16*)(w + OFF_XB);
  __hip_bfloat16* WqkvT = (__hip_bfloat16*)(w + OFF_WQKVT);
  __hip_bfloat16* Qb    = (__hip_bfloat16*)(w + OFF_QB);
  __hip_bfloat16* Kb    = (__hip_bfloat16*)(w + OFF_KB);
  __hip_bfloat16* Vt    = (__hip_bfloat16*)(w + OFF_VT);
  __hip_bfloat16* AO    = (__hip_bfloat16*)(w + OFF_AO);
  __hip_bfloat16* WoutT = (__hip_bfloat16*)(w + OFF_WOUTT);

  // P: prep = C1 (x f32->bf16, 4096 blocks) + T1 (W_qkv transpose, 1536 blocks)
  prep_kernel<<<dim3(4096 + (NQKV / 64) * (Dc / 64)), 256, 0, stream>>>(
      x_q, xb, Wqkv, WqkvT);

  // G1: qkv = x @ W_qkv  (bf16 out)
  gemm_bt<__hip_bfloat16><<<dim3(NQKV / 128, (Bc * Tc) / 128), 256, 0, stream>>>(
      xb, WqkvT, nullptr, qkv, Bc * Tc, NQKV, Dc);

  // RT: rope (Q,K) + V-transpose-from-qkv -> Vt (B,KVH,64,T), one launch
  rope_v_kernel<<<dim3(Bc * Tc + Bc * KVHc * (Tc / 64)), 384, 0, stream>>>(
      qkv, rc, rs, Qb, Kb, Vt);

  // A: flash attention (8 waves, 2 matched tile-pairs/block, shared K/V staging)
  attn_kernel<<<dim3(Tc / 256, Hc, Bc), 512, 0, stream>>>(Qb, Kb, Vt, AO);

  // T2: W_out f32 -> W_out^T bf16
  transpose_cvt_kernel<<<dim3(Dc / 64, Dc / 64), 256, 0, stream>>>(Wout, WoutT, Dc, Dc);

  // G2: out = AO @ W_out + b_out  (f32 out)
  gemm_bt<float><<<dim3(Dc / 128, (Bc * Tc) / 128), 256, 0, stream>>>(
      AO, WoutT, bout, out, Bc * Tc, Dc, Dc);
}